// Round 10
// baseline (116.143 us; speedup 1.0000x reference)
//
#include <hip/hip_runtime.h>
#include <hip/hip_bf16.h>
#include <stdint.h>

#define B 4
#define N 2048
#define DIN 128
#define H 4
#define HD 32
#define NEG 0.2f
#define LOG2E 1.4426950408889634f

typedef __attribute__((ext_vector_type(8))) short short8;
typedef __attribute__((ext_vector_type(4))) float f32x4;

// VT layout: granule-interleaved for coalesced MFMA B-fragment loads.
// VT[bh][j>>3][d][j&7] (ushort): index = ((bh*256 + (j>>3))*32 + d)*8 + (j&7)
// A wave's fragment load (16 lanes, d=lr) = 16 x 16B contiguous = 2 cachelines.

// ---------- Kernel 1: prep = gemm (VT granule layout + ei/ej) ++ adjacency pack ----------
// blocks [0,512): gemm, 16 rows each. blocks [512,16896): pack.
__global__ __launch_bounds__(256) void k_prep(const float* __restrict__ x,
                                              const float* __restrict__ W,
                                              const float* __restrict__ a,
                                              const int* __restrict__ adj,
                                              unsigned short* __restrict__ VT,
                                              float* __restrict__ ei_t,
                                              float* __restrict__ ej_t,
                                              unsigned long long* __restrict__ bits) {
    __shared__ float Wt0[64][64];
    __shared__ float Wt1[64][64];
    __shared__ float xT[64][20];
    __shared__ unsigned short Vl[16][128];   // bf16 tile for transpose-out

    const int tid = threadIdx.x;
    if (blockIdx.x >= 512) {            // ---- pack part ----
        int t = (blockIdx.x - 512) * 256 + tid;
        int v = adj[t];
        unsigned long long m = __ballot(v != 0);
        if ((tid & 63) == 0) bits[t >> 6] = m;
        return;
    }

    // ---- gemm part ----
    const int lane = tid & 63;
    const int r0 = (tid >> 6) * 4;
    const int c2 = lane;
    const int rowBase = blockIdx.x * 16;
    float acc[4][2];
#pragma unroll
    for (int i = 0; i < 4; ++i) { acc[i][0] = 0.f; acc[i][1] = 0.f; }

    for (int kh = 0; kh < 2; ++kh) {
        __syncthreads();
        {   // stage W half, even/odd col planes
            const int c = tid & 127;
            const int qb = (tid >> 7) * 8;
            const int ci = c >> 1, pl = c & 1;
            const float4* W4 = (const float4*)W;
#pragma unroll
            for (int q = 0; q < 8; ++q) {
                float4 v = W4[c * 32 + kh * 16 + qb + q];
                int kk = (qb + q) * 4;
                if (pl == 0) {
                    Wt0[kk + 0][ci] = v.x; Wt0[kk + 1][ci] = v.y;
                    Wt0[kk + 2][ci] = v.z; Wt0[kk + 3][ci] = v.w;
                } else {
                    Wt1[kk + 0][ci] = v.x; Wt1[kk + 1][ci] = v.y;
                    Wt1[kk + 2][ci] = v.z; Wt1[kk + 3][ci] = v.w;
                }
            }
        }
        {   // stage x
            const int rl = tid >> 4;
            const int q = tid & 15;
            float4 v = ((const float4*)x)[(rowBase + rl) * 32 + kh * 16 + q];
            int kk = q * 4;
            xT[kk + 0][rl] = v.x; xT[kk + 1][rl] = v.y;
            xT[kk + 2][rl] = v.z; xT[kk + 3][rl] = v.w;
        }
        __syncthreads();
#pragma unroll 8
        for (int kk = 0; kk < 64; ++kk) {
            float w0 = Wt0[kk][c2];
            float w1 = Wt1[kk][c2];
#pragma unroll
            for (int i = 0; i < 4; ++i) {
                float xv = xT[kk][r0 + i];
                acc[i][0] += xv * w0;
                acc[i][1] += xv * w1;
            }
        }
    }

    const int c0 = 2 * c2;
    const int headT = c0 >> 5, d0 = c0 & 31;
    const int b = rowBase >> 11;
    const int n0 = (rowBase & 2047) + r0;
    const int n0_blk = rowBase & 2047;

    {   // write bf16 tile to LDS: Vl[row][col] (u32 = 2 cols), 2-way bank = free
        unsigned int* Vl32 = (unsigned int*)&Vl[0][0];
#pragma unroll
        for (int i = 0; i < 4; ++i) {
            __hip_bfloat16 h0 = __float2bfloat16(acc[i][0]);
            __hip_bfloat16 h1 = __float2bfloat16(acc[i][1]);
            unsigned int v = (unsigned int)*(unsigned short*)&h0 |
                             ((unsigned int)*(unsigned short*)&h1 << 16);
            Vl32[(r0 + i) * 64 + c2] = v;
        }
    }
    {   // ei/ej (log2e-scaled) from acc via shuffles (independent of LDS)
        float a10 = a[headT * 64 + d0],      a11 = a[headT * 64 + d0 + 1];
        float a20 = a[headT * 64 + 32 + d0], a21 = a[headT * 64 + 32 + d0 + 1];
        const int bh_e = b * 4 + headT;
#pragma unroll
        for (int i = 0; i < 4; ++i) {
            float pi = acc[i][0] * a10 + acc[i][1] * a11;
            float pj = acc[i][0] * a20 + acc[i][1] * a21;
#pragma unroll
            for (int off = 1; off < 16; off <<= 1) {
                pi += __shfl_xor(pi, off);
                pj += __shfl_xor(pj, off);
            }
            if ((lane & 15) == 0) {
                ei_t[(size_t)bh_e * 2048 + n0 + i] = pi * LOG2E;
                ej_t[(size_t)bh_e * 2048 + n0 + i] = pj * LOG2E;
            }
        }
    }
    __syncthreads();
    {   // coalesced VT store: thread t -> (d = t>>1, nh = t&1), 16B each
        const int d = tid >> 1, nh = tid & 1;
        const int hd_ = d >> 5, d31 = d & 31;
        const int bh = b * 4 + hd_;
        const int gran = (n0_blk >> 3) + nh;
        ushort4 o0, o1;
        unsigned short* q = (unsigned short*)&o0;
#pragma unroll
        for (int k = 0; k < 4; ++k) q[k] = Vl[nh * 8 + k][d];
        q = (unsigned short*)&o1;
#pragma unroll
        for (int k = 0; k < 4; ++k) q[k] = Vl[nh * 8 + 4 + k][d];
        unsigned short* dst = &VT[((size_t)(bh * 256 + gran) * 32 + d31) * 8];
        *(ushort4*)&dst[0] = o0;
        *(ushort4*)&dst[4] = o1;
    }
}

// ---------- Kernel 2: MFMA attention, coalesced global V, no staging ----------
// grid 512 = b(4) x head(4) x rowtile(32 of 64 rows); block = 8 waves =
// wtile(4 subtiles of 16 rows) x par(2 j-parities of 64-j chunks).
// Depth-1 named-register pipeline on fragments+mask; sched_barrier pins issue.
__global__ __launch_bounds__(512, 4) void k_attn_c(const unsigned short* __restrict__ VT,
                                                   const float* __restrict__ ei_t,
                                                   const float* __restrict__ ej_t,
                                                   const unsigned long long* __restrict__ bits,
                                                   float* __restrict__ out) {
    __shared__ float red[4][64][13];   // [wtile][lane][12 vals], pad 13

    const int tid = threadIdx.x;
    const int bid = blockIdx.x;
    const int rt = bid & 31;
    const int head = (bid >> 5) & 3;
    const int b = bid >> 7;
    const int wv = tid >> 6, lane = tid & 63;
    const int wtile = wv & 3, par = wv >> 2;
    const int lr = lane & 15;
    const int g = lane >> 4;
    const int rowW = rt * 64 + wtile * 16;
    const int bh = b * 4 + head;

    const unsigned short* VTb = VT + (size_t)bh * 256 * 32 * 8;
    const float* ejp = ej_t + (size_t)bh * 2048;
    const float eir = ei_t[(size_t)bh * 2048 + rowW + lr];
    const unsigned long long* mrow = bits + (size_t)(rowW + lr) * (N / 64);

    f32x4 acc0 = {0.f, 0.f, 0.f, 0.f};
    f32x4 acc1 = {0.f, 0.f, 0.f, 0.f};
    f32x4 accS = {0.f, 0.f, 0.f, 0.f};
    short8 onesb;
    {
        short ov = (lr == 0) ? (short)0x3F80 : (short)0;   // bf16 1.0 in col 0
#pragma unroll
        for (int e = 0; e < 8; ++e) onesb[e] = ov;
    }

    // fragment address: granule (j32>>3)+g, element d
    auto FR = [&](int j32, int dbase) -> const short8* {
        return (const short8*)&VTb[((size_t)(((j32) >> 3) + g) * 32 + dbase + lr) * 8];
    };

    int jc = par * 64;
    unsigned long long wA = mrow[jc >> 6];
    short8 a00 = *FR(jc, 0),      a10 = *FR(jc, 16);        // ks=0
    short8 a01 = *FR(jc + 32, 0), a11 = *FR(jc + 32, 16);   // ks=1

#pragma unroll 1
    for (int it = 0; it < 16; ++it) {
        int jn = jc + 128; if (jn >= N) jn = par * 64;      // last prefetch wraps
        unsigned long long wB = mrow[jn >> 6];
        short8 n00 = *FR(jn, 0),      n10 = *FR(jn, 16);
        short8 n01 = *FR(jn + 32, 0), n11 = *FR(jn + 32, 16);
        __builtin_amdgcn_sched_barrier(0);                  // pin prefetch issue

#pragma unroll
        for (int ks = 0; ks < 2; ++ks) {
            const int joff = jc + ks * 32 + g * 8;
            float4 ea = *(const float4*)&ejp[joff];
            float4 eb = *(const float4*)&ejp[joff + 4];
            const unsigned int mb = (unsigned int)(wA >> (ks * 32 + g * 8)) & 0xffu;
            float ej8[8] = {ea.x, ea.y, ea.z, ea.w, eb.x, eb.y, eb.z, eb.w};
            short8 pa;
#pragma unroll
            for (int e = 0; e < 8; ++e) {
                float s = eir + ej8[e];                     // log2-domain score
                float el = fmaxf(s, NEG * s);               // exact leaky-relu
                float p = ((mb >> e) & 1u) ? __builtin_amdgcn_exp2f(el) : 0.f;
                __hip_bfloat16 pb = __float2bfloat16(p);
                pa[e] = (short)*(unsigned short*)&pb;
            }
            short8 u0 = ks ? a01 : a00;
            short8 u1 = ks ? a11 : a10;
            acc0 = __builtin_amdgcn_mfma_f32_16x16x32_bf16(pa, u0, acc0, 0, 0, 0);
            acc1 = __builtin_amdgcn_mfma_f32_16x16x32_bf16(pa, u1, acc1, 0, 0, 0);
            accS = __builtin_amdgcn_mfma_f32_16x16x32_bf16(pa, onesb, accS, 0, 0, 0);
        }
        wA = wB; a00 = n00; a10 = n10; a01 = n01; a11 = n11;
        jc = jn;
    }

    // combine the 2 j-parities through LDS
    if (par == 1) {
        float* r = &red[wtile][lane][0];
#pragma unroll
        for (int q = 0; q < 4; ++q) {
            r[q] = acc0[q]; r[4 + q] = acc1[q]; r[8 + q] = accS[q];
        }
    }
    __syncthreads();
    if (par == 0) {
        const float* r = &red[wtile][lane][0];
#pragma unroll
        for (int q = 0; q < 4; ++q) {
            acc0[q] += r[q]; acc1[q] += r[4 + q]; accS[q] += r[8 + q];
        }
        // C/D layout (HW-verified): col = lane&15, row = 4*(lane>>4)+reg.
#pragma unroll
        for (int reg = 0; reg < 4; ++reg) {
            const float sr = __shfl(accS[reg], g * 16);
            const float inv = 1.f / sr;
            const int m = 4 * g + reg;
            float* dst = &out[(size_t)(b * N + rowW + m) * 128 + head * 32 + lr];
            dst[0]  = acc0[reg] * inv;
            dst[16] = acc1[reg] * inv;
        }
    }
}

// ================= FALLBACK: ZERO-WORKSPACE FUSED KERNEL =================
__global__ __launch_bounds__(256) void k_fused(const float* __restrict__ x,
                                               const int* __restrict__ adj,
                                               const float* __restrict__ W,
                                               const float* __restrict__ a,
                                               float* __restrict__ out) {
    __shared__ float Ws[32][129];
    __shared__ float xs[64][132];
    __shared__ float hs[64][44];
    __shared__ float ejs[64];
    __shared__ float eis[128];
    __shared__ float a1s[32], a2s[32];
    __shared__ unsigned long long mb[128];

    const int tid = threadIdx.x;
    const int bid = blockIdx.x;
    const int rt = bid & 15;
    const int head = (bid >> 4) & 3;
    const int b = bid >> 6;
    const int row0 = rt * 128;

    for (int idx = tid; idx < 32 * 128; idx += 256) {
        int d = idx >> 7, k = idx & 127;
        Ws[d][k] = W[(head * 32 + d) * 128 + k];
    }
    if (tid < 32) a1s[tid] = a[head * 64 + tid];
    else if (tid < 64) a2s[tid - 32] = a[head * 64 + tid];
    __syncthreads();

    for (int c0 = 0; c0 < 128; c0 += 64) {
        __syncthreads();
        {
            int jj = tid >> 2, k0 = (tid & 3) * 32;
            const float4* src = (const float4*)&x[(b * N + row0 + c0 + jj) * 128 + k0];
#pragma unroll
            for (int q = 0; q < 8; ++q) *(float4*)&xs[jj][k0 + q * 4] = src[q];
        }
        __syncthreads();
        {
            int jj = tid >> 2, db = (tid & 3) * 8;
#pragma unroll
            for (int dd = 0; dd < 8; ++dd) {
                float s = 0.f;
                for (int k = 0; k < 128; ++k) s += xs[jj][k] * Ws[db + dd][k];
                hs[jj][db + dd] = s;
            }
        }
        __syncthreads();
        if (tid < 64) {
            float s = 0.f;
#pragma unroll
            for (int d = 0; d < 32; ++d) s += hs[tid][d] * a1s[d];
            eis[c0 + tid] = s;
        }
    }

    const int dgrp = tid & 3, d0 = dgrp * 8;
    const int rseg = tid >> 2;
    float acc[2][8];
    float sacc[2] = {0.f, 0.f};
#pragma unroll
    for (int k = 0; k < 2; ++k)
#pragma unroll
        for (int d = 0; d < 8; ++d) acc[k][d] = 0.f;

    for (int jc = 0; jc < N; jc += 64) {
        __syncthreads();
        {
            int jj = tid >> 2, k0 = (tid & 3) * 32;
            const float4* src = (const float4*)&x[(b * N + jc + jj) * 128 + k0];
#pragma unroll
            for (int q = 0; q < 8; ++q) *(float4*)&xs[jj][k0 + q * 4] = src[q];
        }
        {
            int wv = tid >> 6, lane = tid & 63;
            for (int p = 0; p < 32; ++p) {
                int il = p * 4 + wv;
                unsigned long long m = __ballot(adj[(row0 + il) * N + jc + lane] != 0);
                if (lane == 0) mb[il] = m;
            }
        }
        __syncthreads();
        {
            int jj = tid >> 2, db = (tid & 3) * 8;
#pragma unroll
            for (int dd = 0; dd < 8; ++dd) {
                float s = 0.f;
                for (int k = 0; k < 128; ++k) s += xs[jj][k] * Ws[db + dd][k];
                hs[jj][db + dd] = s;
            }
        }
        __syncthreads();
        if (tid < 64) {
            float s = 0.f;
#pragma unroll
            for (int d = 0; d < 32; ++d) s += hs[tid][d] * a2s[d];
            ejs[tid] = s;
        }
        __syncthreads();
        for (int jj = 0; jj < 64; ++jj) {
            float ejv = ejs[jj];
            float hv[8];
#pragma unroll
            for (int d = 0; d < 8; ++d) hv[d] = hs[jj][d0 + d];
#pragma unroll
            for (int k = 0; k < 2; ++k) {
                int il = rseg * 2 + k;
                float s = eis[il] + ejv;
                float el = s > 0.f ? s : NEG * s;
                float p = ((mb[il] >> jj) & 1ull) ? __expf(el) : 0.f;
                sacc[k] += p;
#pragma unroll
                for (int d = 0; d < 8; ++d) acc[k][d] += p * hv[d];
            }
        }
    }
#pragma unroll
    for (int k = 0; k < 2; ++k) {
        int il = rseg * 2 + k;
        float inv = 1.f / sacc[k];
        float* dst = &out[(b * N + row0 + il) * 128 + head * 32 + d0];
#pragma unroll
        for (int d = 0; d < 8; ++d) dst[d] = acc[k][d] * inv;
    }
}

extern "C" void kernel_launch(void* const* d_in, const int* in_sizes, int n_in,
                              void* d_out, int out_size, void* d_ws, size_t ws_size,
                              hipStream_t stream) {
    // Identify inputs by element count (all unique) — order-proof.
    const float* x = nullptr; const int* adj = nullptr;
    const float* W = nullptr; const float* a = nullptr;
    for (int i = 0; i < n_in; ++i) {
        switch (in_sizes[i]) {
            case B * N * DIN:  x   = (const float*)d_in[i]; break;  // 1048576
            case N * N:        adj = (const int*)d_in[i];   break;  // 4194304
            case H * HD * DIN: W   = (const float*)d_in[i]; break;  // 16384
            case H * 2 * HD:   a   = (const float*)d_in[i]; break;  // 256
        }
    }
    float* out = (float*)d_out;   // reference output dtype is float32

    // ws: VT bf16 2MB | ei_t 128KB | ej_t 128KB | bits 512KB  = 2.75 MB
    const size_t szVT = (size_t)B * H * HD * N * 2;
    const size_t szE  = (size_t)B * H * N * 4;
    const size_t szBits = (size_t)N * (N / 64) * 8;
    const size_t need = szVT + 2 * szE + szBits;

    if (ws_size >= need) {
        char* ws = (char*)d_ws;
        unsigned short* VT = (unsigned short*)ws;
        float* ei_t = (float*)(ws + szVT);
        float* ej_t = (float*)(ws + szVT + szE);
        unsigned long long* bits = (unsigned long long*)(ws + szVT + 2 * szE);

        k_prep<<<512 + (N * N) / 256, 256, 0, stream>>>(x, W, a, adj, VT, ei_t, ej_t, bits);
        k_attn_c<<<512, 512, 0, stream>>>(VT, ei_t, ej_t, bits, out);
    } else {
        k_fused<<<256, 256, 0, stream>>>(x, adj, W, a, out);
    }
}

// Round 11
// 110.980 us; speedup vs baseline: 1.0465x; 1.0465x over previous
//
#include <hip/hip_runtime.h>
#include <hip/hip_bf16.h>
#include <stdint.h>

#define B 4
#define N 2048
#define DIN 128
#define H 4
#define HD 32
#define NEG 0.2f
#define LOG2E 1.4426950408889634f
#define WINJ 256

typedef __attribute__((ext_vector_type(8))) short short8;
typedef __attribute__((ext_vector_type(4))) float f32x4;

// VT layout: [bh][d][window(8) | swizzled granule slot(32) | elem(8)] bf16.
// slot = gw ^ (d&7) where gw = logical granule (j>>3) within window.
// bitsT layout: [jword(32)][row(2048)] u64 — wave loads its window's masks
// (4 jwords x 16 rows) in ONE coalesced 128B load.

// ---------- Kernel 1: prep = gemm (VT swizzled + ei/ej) ++ adjacency pack ----------
// blocks [0,512): gemm, 16 rows each. blocks [512,16896): pack.
__global__ __launch_bounds__(256) void k_prep(const float* __restrict__ x,
                                              const float* __restrict__ W,
                                              const float* __restrict__ a,
                                              const int* __restrict__ adj,
                                              unsigned short* __restrict__ VT,
                                              float* __restrict__ ei_t,
                                              float* __restrict__ ej_t,
                                              unsigned long long* __restrict__ bitsT) {
    __shared__ float Wt0[64][64];
    __shared__ float Wt1[64][64];
    __shared__ float xT[64][20];

    const int tid = threadIdx.x;
    if (blockIdx.x >= 512) {            // ---- pack part ----
        int t = (blockIdx.x - 512) * 256 + tid;
        int v = adj[t];
        unsigned long long m = __ballot(v != 0);
        if ((tid & 63) == 0) {
            int row = t >> 11, jw = (t >> 6) & 31;
            bitsT[(size_t)jw * 2048 + row] = m;
        }
        return;
    }

    // ---- gemm part ----
    const int lane = tid & 63;
    const int r0 = (tid >> 6) * 4;
    const int c2 = lane;
    const int rowBase = blockIdx.x * 16;
    float acc[4][2];
#pragma unroll
    for (int i = 0; i < 4; ++i) { acc[i][0] = 0.f; acc[i][1] = 0.f; }

    for (int kh = 0; kh < 2; ++kh) {
        __syncthreads();
        {   // stage W half, even/odd col planes
            const int c = tid & 127;
            const int qb = (tid >> 7) * 8;
            const int ci = c >> 1, pl = c & 1;
            const float4* W4 = (const float4*)W;
#pragma unroll
            for (int q = 0; q < 8; ++q) {
                float4 v = W4[c * 32 + kh * 16 + qb + q];
                int kk = (qb + q) * 4;
                if (pl == 0) {
                    Wt0[kk + 0][ci] = v.x; Wt0[kk + 1][ci] = v.y;
                    Wt0[kk + 2][ci] = v.z; Wt0[kk + 3][ci] = v.w;
                } else {
                    Wt1[kk + 0][ci] = v.x; Wt1[kk + 1][ci] = v.y;
                    Wt1[kk + 2][ci] = v.z; Wt1[kk + 3][ci] = v.w;
                }
            }
        }
        {   // stage x
            const int rl = tid >> 4;
            const int q = tid & 15;
            float4 v = ((const float4*)x)[(rowBase + rl) * 32 + kh * 16 + q];
            int kk = q * 4;
            xT[kk + 0][rl] = v.x; xT[kk + 1][rl] = v.y;
            xT[kk + 2][rl] = v.z; xT[kk + 3][rl] = v.w;
        }
        __syncthreads();
#pragma unroll 8
        for (int kk = 0; kk < 64; ++kk) {
            float w0 = Wt0[kk][c2];
            float w1 = Wt1[kk][c2];
#pragma unroll
            for (int i = 0; i < 4; ++i) {
                float xv = xT[kk][r0 + i];
                acc[i][0] += xv * w0;
                acc[i][1] += xv * w1;
            }
        }
    }

    const int c0 = 2 * c2;
    const int headT = c0 >> 5, d0 = c0 & 31;
    const int b = rowBase >> 11;
    const int n0 = (rowBase & 2047) + r0;
    const int bh = b * 4 + headT;

    {   // V^T bf16, PRE-SWIZZLED within 256-j window: slot = gw ^ (d&7)
        ushort4 p0, p1;
        unsigned short* q0 = (unsigned short*)&p0;
        unsigned short* q1 = (unsigned short*)&p1;
#pragma unroll
        for (int i = 0; i < 4; ++i) {
            __hip_bfloat16 h0 = __float2bfloat16(acc[i][0]);
            __hip_bfloat16 h1 = __float2bfloat16(acc[i][1]);
            q0[i] = *(unsigned short*)&h0;
            q1[i] = *(unsigned short*)&h1;
        }
        const int wdw = n0 >> 8;
        const int gw  = (n0 >> 3) & 31;
        const int off = n0 & 7;                // 0 or 4 (8B-aligned half-granule)
        const int gs0 = gw ^ (d0 & 7);
        const int gs1 = gw ^ ((d0 + 1) & 7);
        *(ushort4*)&VT[((size_t)bh * 32 + d0) * 2048 + wdw * WINJ + gs0 * 8 + off] = p0;
        *(ushort4*)&VT[((size_t)bh * 32 + d0 + 1) * 2048 + wdw * WINJ + gs1 * 8 + off] = p1;
    }
    {   // ei/ej (log2e-scaled), f32 precision
        float a10 = a[headT * 64 + d0],      a11 = a[headT * 64 + d0 + 1];
        float a20 = a[headT * 64 + 32 + d0], a21 = a[headT * 64 + 32 + d0 + 1];
#pragma unroll
        for (int i = 0; i < 4; ++i) {
            float pi = acc[i][0] * a10 + acc[i][1] * a11;
            float pj = acc[i][0] * a20 + acc[i][1] * a21;
#pragma unroll
            for (int off = 1; off < 16; off <<= 1) {
                pi += __shfl_xor(pi, off);
                pj += __shfl_xor(pj, off);
            }
            if ((lane & 15) == 0) {
                ei_t[(size_t)bh * 2048 + n0 + i] = pi * LOG2E;
                ej_t[(size_t)bh * 2048 + n0 + i] = pj * LOG2E;
            }
        }
    }
}

// ---------- Kernel 2: MFMA attention, LDS-windowed dbuf, 256-j windows ----------
// grid 512 = b(4) x head(4) x rowtile(32 of 64 rows); block = 4 waves x 16 rows.
// 2 blocks/CU; reg-staged dbuf (issue-early/write-late); one mask load/window.
__global__ __launch_bounds__(256) void k_attn_w(const unsigned short* __restrict__ VT,
                                                const float* __restrict__ ei_t,
                                                const float* __restrict__ ej_t,
                                                const unsigned long long* __restrict__ bitsT,
                                                float* __restrict__ out) {
    __shared__ __align__(16) unsigned short Vs[2][32 * WINJ];   // 2 x 16KB
    __shared__ __align__(16) float ejs[2][WINJ];                // 2 x 1KB

    const int tid = threadIdx.x;
    const int bid = blockIdx.x;
    const int rt = bid & 31;
    const int head = (bid >> 5) & 3;
    const int b = bid >> 7;
    const int wv = tid >> 6, lane = tid & 63;
    const int lr = lane & 15;
    const int g = lane >> 4;
    const int rowW = rt * 64 + wv * 16;
    const int bh = b * 4 + head;

    const unsigned short* VTb = VT + (size_t)bh * 32 * 2048;
    const float* ejg = ej_t + (size_t)bh * 2048;
    const float eir = ei_t[(size_t)bh * 2048 + rowW + lr];

    f32x4 acc0 = {0.f, 0.f, 0.f, 0.f};
    f32x4 acc1 = {0.f, 0.f, 0.f, 0.f};
    f32x4 accS = {0.f, 0.f, 0.f, 0.f};
    short8 onesb;
    {
        short ov = (lr == 0) ? (short)0x3F80 : (short)0;   // bf16 1.0 in col 0
#pragma unroll
        for (int e = 0; e < 8; ++e) onesb[e] = ov;
    }

    // ---- prologue: stage window 0 (1024 granules, 4 per thread) ----
    {
#pragma unroll
        for (int i = 0; i < 4; ++i) {
            int L = i * 256 + tid, d = L >> 5, gr = L & 31;
            float4 v = *(const float4*)&VTb[(size_t)d * 2048 + gr * 8];
            *(float4*)&Vs[0][(size_t)L * 8] = v;
        }
        if (tid < 64) {
            float4 e = *(const float4*)&ejg[tid * 4];
            *(float4*)&ejs[0][tid * 4] = e;
        }
    }
    __syncthreads();

    for (int w = 0; w < 8; ++w) {
        const int buf = w & 1;
        // all mask words for this window: lane (g,lr) -> (jword w*4+g, row rowW+lr)
        const unsigned long long wreg =
            bitsT[(size_t)(w * 4 + g) * 2048 + rowW + lr];

        float4 vr0, vr1, vr2, vr3, er;
        const bool pf = (w < 7);
        if (pf) {   // issue next-window loads EARLY
            const unsigned short* src = VTb + (w + 1) * WINJ;
            vr0 = *(const float4*)&src[(size_t)((tid)        >> 5) * 2048 + ((tid)        & 31) * 8];
            vr1 = *(const float4*)&src[(size_t)((256 + tid)  >> 5) * 2048 + ((256 + tid)  & 31) * 8];
            vr2 = *(const float4*)&src[(size_t)((512 + tid)  >> 5) * 2048 + ((512 + tid)  & 31) * 8];
            vr3 = *(const float4*)&src[(size_t)((768 + tid)  >> 5) * 2048 + ((768 + tid)  & 31) * 8];
            if (tid < 64) er = *(const float4*)&ejg[(w + 1) * WINJ + tid * 4];
        }
        __builtin_amdgcn_sched_barrier(0);   // pin load issue before compute

        const unsigned short* Vb = &Vs[buf][0];
        const float* ejb = &ejs[buf][0];
#pragma unroll
        for (int jl = 0; jl < WINJ; jl += 64) {
            const unsigned long long word = __shfl(wreg, (jl >> 6) * 16 + lr);
#pragma unroll
            for (int ks = 0; ks < 2; ++ks) {
                const int gw_ = (jl >> 3) + ks * 4 + g;       // logical granule
                const int slot = gw_ ^ (lr & 7);
                short8 b0 = *(const short8*)&Vb[lr * WINJ + slot * 8];
                short8 b1 = *(const short8*)&Vb[(16 + lr) * WINJ + slot * 8];
                const int f = jl + ks * 32 + g * 8;
                float4 ea = *(const float4*)&ejb[f];
                float4 eb = *(const float4*)&ejb[f + 4];
                const unsigned int mb =
                    (unsigned int)(word >> (ks * 32 + g * 8)) & 0xffu;
                float ej8[8] = {ea.x, ea.y, ea.z, ea.w, eb.x, eb.y, eb.z, eb.w};
                short8 pa;
#pragma unroll
                for (int e = 0; e < 8; ++e) {
                    float s = eir + ej8[e];                  // log2-domain score
                    float el = fmaxf(s, NEG * s);            // exact leaky-relu
                    float p = ((mb >> e) & 1u) ? __builtin_amdgcn_exp2f(el) : 0.f;
                    __hip_bfloat16 pb = __float2bfloat16(p);
                    pa[e] = (short)*(unsigned short*)&pb;
                }
                __builtin_amdgcn_s_setprio(1);
                acc0 = __builtin_amdgcn_mfma_f32_16x16x32_bf16(pa, b0, acc0, 0, 0, 0);
                acc1 = __builtin_amdgcn_mfma_f32_16x16x32_bf16(pa, b1, acc1, 0, 0, 0);
                accS = __builtin_amdgcn_mfma_f32_16x16x32_bf16(pa, onesb, accS, 0, 0, 0);
                __builtin_amdgcn_s_setprio(0);
            }
        }

        if (pf) {   // write-late into the other buffer
            const int nbuf = buf ^ 1;
            *(float4*)&Vs[nbuf][(size_t)tid * 8]          = vr0;
            *(float4*)&Vs[nbuf][(size_t)(256 + tid) * 8]  = vr1;
            *(float4*)&Vs[nbuf][(size_t)(512 + tid) * 8]  = vr2;
            *(float4*)&Vs[nbuf][(size_t)(768 + tid) * 8]  = vr3;
            if (tid < 64) *(float4*)&ejs[nbuf][tid * 4] = er;
        }
        __syncthreads();
    }

    // ---- epilogue: rowsum from ones-MFMA col0, normalize, store ----
    // C/D layout (HW-verified): col = lane&15, row = 4*(lane>>4)+reg.
#pragma unroll
    for (int reg = 0; reg < 4; ++reg) {
        const float sr = __shfl(accS[reg], g * 16);
        const float inv = 1.f / sr;
        const int m = 4 * g + reg;
        float* dst = &out[(size_t)(b * N + rowW + m) * 128 + head * 32 + lr];
        dst[0]  = acc0[reg] * inv;
        dst[16] = acc1[reg] * inv;
    }
}

// ================= FALLBACK: ZERO-WORKSPACE FUSED KERNEL =================
__global__ __launch_bounds__(256) void k_fused(const float* __restrict__ x,
                                               const int* __restrict__ adj,
                                               const float* __restrict__ W,
                                               const float* __restrict__ a,
                                               float* __restrict__ out) {
    __shared__ float Ws[32][129];
    __shared__ float xs[64][132];
    __shared__ float hs[64][44];
    __shared__ float ejs[64];
    __shared__ float eis[128];
    __shared__ float a1s[32], a2s[32];
    __shared__ unsigned long long mb[128];

    const int tid = threadIdx.x;
    const int bid = blockIdx.x;
    const int rt = bid & 15;
    const int head = (bid >> 4) & 3;
    const int b = bid >> 6;
    const int row0 = rt * 128;

    for (int idx = tid; idx < 32 * 128; idx += 256) {
        int d = idx >> 7, k = idx & 127;
        Ws[d][k] = W[(head * 32 + d) * 128 + k];
    }
    if (tid < 32) a1s[tid] = a[head * 64 + tid];
    else if (tid < 64) a2s[tid - 32] = a[head * 64 + tid];
    __syncthreads();

    for (int c0 = 0; c0 < 128; c0 += 64) {
        __syncthreads();
        {
            int jj = tid >> 2, k0 = (tid & 3) * 32;
            const float4* src = (const float4*)&x[(b * N + row0 + c0 + jj) * 128 + k0];
#pragma unroll
            for (int q = 0; q < 8; ++q) *(float4*)&xs[jj][k0 + q * 4] = src[q];
        }
        __syncthreads();
        {
            int jj = tid >> 2, db = (tid & 3) * 8;
#pragma unroll
            for (int dd = 0; dd < 8; ++dd) {
                float s = 0.f;
                for (int k = 0; k < 128; ++k) s += xs[jj][k] * Ws[db + dd][k];
                hs[jj][db + dd] = s;
            }
        }
        __syncthreads();
        if (tid < 64) {
            float s = 0.f;
#pragma unroll
            for (int d = 0; d < 32; ++d) s += hs[tid][d] * a1s[d];
            eis[c0 + tid] = s;
        }
    }

    const int dgrp = tid & 3, d0 = dgrp * 8;
    const int rseg = tid >> 2;
    float acc[2][8];
    float sacc[2] = {0.f, 0.f};
#pragma unroll
    for (int k = 0; k < 2; ++k)
#pragma unroll
        for (int d = 0; d < 8; ++d) acc[k][d] = 0.f;

    for (int jc = 0; jc < N; jc += 64) {
        __syncthreads();
        {
            int jj = tid >> 2, k0 = (tid & 3) * 32;
            const float4* src = (const float4*)&x[(b * N + jc + jj) * 128 + k0];
#pragma unroll
            for (int q = 0; q < 8; ++q) *(float4*)&xs[jj][k0 + q * 4] = src[q];
        }
        {
            int wv = tid >> 6, lane = tid & 63;
            for (int p = 0; p < 32; ++p) {
                int il = p * 4 + wv;
                unsigned long long m = __ballot(adj[(row0 + il) * N + jc + lane] != 0);
                if (lane == 0) mb[il] = m;
            }
        }
        __syncthreads();
        {
            int jj = tid >> 2, db = (tid & 3) * 8;
#pragma unroll
            for (int dd = 0; dd < 8; ++dd) {
                float s = 0.f;
                for (int k = 0; k < 128; ++k) s += xs[jj][k] * Ws[db + dd][k];
                hs[jj][db + dd] = s;
            }
        }
        __syncthreads();
        if (tid < 64) {
            float s = 0.f;
#pragma unroll
            for (int d = 0; d < 32; ++d) s += hs[tid][d] * a2s[d];
            ejs[tid] = s;
        }
        __syncthreads();
        for (int jj = 0; jj < 64; ++jj) {
            float ejv = ejs[jj];
            float hv[8];
#pragma unroll
            for (int d = 0; d < 8; ++d) hv[d] = hs[jj][d0 + d];
#pragma unroll
            for (int k = 0; k < 2; ++k) {
                int il = rseg * 2 + k;
                float s = eis[il] + ejv;
                float el = s > 0.f ? s : NEG * s;
                float p = ((mb[il] >> jj) & 1ull) ? __expf(el) : 0.f;
                sacc[k] += p;
#pragma unroll
                for (int d = 0; d < 8; ++d) acc[k][d] += p * hv[d];
            }
        }
    }
#pragma unroll
    for (int k = 0; k < 2; ++k) {
        int il = rseg * 2 + k;
        float inv = 1.f / sacc[k];
        float* dst = &out[(b * N + row0 + il) * 128 + head * 32 + d0];
#pragma unroll
        for (int d = 0; d < 8; ++d) dst[d] = acc[k][d] * inv;
    }
}

extern "C" void kernel_launch(void* const* d_in, const int* in_sizes, int n_in,
                              void* d_out, int out_size, void* d_ws, size_t ws_size,
                              hipStream_t stream) {
    // Identify inputs by element count (all unique) — order-proof.
    const float* x = nullptr; const int* adj = nullptr;
    const float* W = nullptr; const float* a = nullptr;
    for (int i = 0; i < n_in; ++i) {
        switch (in_sizes[i]) {
            case B * N * DIN:  x   = (const float*)d_in[i]; break;  // 1048576
            case N * N:        adj = (const int*)d_in[i];   break;  // 4194304
            case H * HD * DIN: W   = (const float*)d_in[i]; break;  // 16384
            case H * 2 * HD:   a   = (const float*)d_in[i]; break;  // 256
        }
    }
    float* out = (float*)d_out;   // reference output dtype is float32

    // ws: VT bf16 2MB | ei_t 128KB | ej_t 128KB | bitsT 512KB  = 2.75 MB
    const size_t szVT = (size_t)B * H * HD * N * 2;
    const size_t szE  = (size_t)B * H * N * 4;
    const size_t szBits = (size_t)N * (N / 64) * 8;
    const size_t need = szVT + 2 * szE + szBits;

    if (ws_size >= need) {
        char* ws = (char*)d_ws;
        unsigned short* VT = (unsigned short*)ws;
        float* ei_t = (float*)(ws + szVT);
        float* ej_t = (float*)(ws + szVT + szE);
        unsigned long long* bitsT = (unsigned long long*)(ws + szVT + 2 * szE);

        k_prep<<<512 + (N * N) / 256, 256, 0, stream>>>(x, W, a, adj, VT, ei_t, ej_t, bitsT);
        k_attn_w<<<512, 256, 0, stream>>>(VT, ei_t, ej_t, bitsT, out);
    } else {
        k_fused<<<256, 256, 0, stream>>>(x, adj, W, a, out);
    }
}